// Round 4
// baseline (444.492 us; speedup 1.0000x reference)
//
// R4: 32x32x16 MFMA both GEMMs; gemm1 128x128 fused gate/up tile; gemm2 K-split x2
// with bf16 partial Obuf slices; gather+convert fused. 5 launches.
#include <hip/hip_runtime.h>
#include <stdint.h>

#define TOKS 4096
#define DIM  1024
#define HID  2048
#define OUTD 1024
#define NE   8
#define MP   9216
#define NBR  72

typedef __bf16 bf16;
typedef bf16 bf16x8 __attribute__((ext_vector_type(8)));
typedef float f32x16 __attribute__((ext_vector_type(16)));
typedef __attribute__((address_space(1))) void gvoid;
typedef __attribute__((address_space(3))) void lvoid;

// ---- workspace byte offsets ----
#define WGU_OFF  0ull                         // 64MB bf16 weights; O-slices (2x18.9MB bf16) alias after gemm1
#define WD_OFF   (WGU_OFF + 67108864ull)
#define XG_OFF   (WD_OFF  + 33554432ull)      // MP*1024*2
#define H_OFF    (XG_OFF  + 18874368ull)      // MP*2048*2
#define TK_OFF   (H_OFF   + 37748736ull)      // MP*4
#define META_OFF (TK_OFF  + 36864ull)         // table NBR ints
#define T2S_OFF  (META_OFF + 1024ull)         // TOKS*2 ints
#define O0_OFF   WGU_OFF                      // MP*OUTD bf16 = 18874368
#define O1_OFF   (WGU_OFF + 18874368ull)

__device__ __forceinline__ unsigned short f2bf(float f) {
  union { float f; unsigned u; } v; v.f = f;
  unsigned r = (v.u + 0x7FFFu + ((v.u >> 16) & 1u)) >> 16;
  return (unsigned short)r;
}
__device__ __forceinline__ float bf2f(unsigned short h) {
  union { unsigned u; float f; } v; v.u = ((unsigned)h) << 16; return v.f;
}
__device__ __forceinline__ unsigned pack2(float a, float b) {
  return (unsigned)f2bf(a) | ((unsigned)f2bf(b) << 16);
}
__device__ __forceinline__ void cp16(const void* g, void* l) {
  __builtin_amdgcn_global_load_lds((gvoid*)(void*)g, (lvoid*)l, 16, 0, 0);
}

// ---------- routing ----------
__global__ __launch_bounds__(1024) void route_kernel(const int* __restrict__ idx,
                                                     int* __restrict__ table,
                                                     int* __restrict__ slot_token,
                                                     int* __restrict__ tok2slot) {
  __shared__ int cnt[NE], offs[NE], cur[NE];
  const int tid = threadIdx.x, lane = tid & 63;
  for (int i = tid; i < MP; i += 1024) slot_token[i] = -1;
  if (tid < NE) cnt[tid] = 0;
  __syncthreads();
  int myE[8];
#pragma unroll
  for (int c = 0; c < 8; ++c) myE[c] = idx[c * 1024 + tid];
#pragma unroll
  for (int c = 0; c < 8; ++c) {
    int e = myE[c];
#pragma unroll
    for (int ex = 0; ex < NE; ++ex) {
      unsigned long long m = __ballot(e == ex);
      if (lane == 0 && m) atomicAdd(&cnt[ex], __popcll(m));
    }
  }
  __syncthreads();
  if (tid == 0) {
    int cum = 0;
    for (int e = 0; e < NE; ++e) {
      offs[e] = cum; cur[e] = 0;
      int nb = (cnt[e] + 127) >> 7;
      int bb = cum >> 7;
      for (int b = 0; b < nb; ++b) table[bb + b] = e;
      cum += nb << 7;
    }
    for (int b = cum >> 7; b < NBR; ++b) table[b] = -1;
  }
  __syncthreads();
#pragma unroll
  for (int c = 0; c < 8; ++c) {
    int e = myE[c];
    int pos = 0;
#pragma unroll
    for (int ex = 0; ex < NE; ++ex) {
      unsigned long long m = __ballot(e == ex);
      if (e == ex) {
        int rank = __popcll(m & ((1ull << lane) - 1ull));
        int leader = __ffsll(m) - 1;
        int base = 0;
        if (lane == leader) base = atomicAdd(&cur[ex], __popcll(m));
        base = __shfl(base, leader);
        pos = offs[ex] + base + rank;
      }
    }
    slot_token[pos] = (c * 1024 + tid) >> 1;
    tok2slot[c * 1024 + tid] = pos;
  }
}

// ---------- fused gather (X->Xg bf16) + weight convert ----------
#define GATHER_B 4608   // MP*128/256
__global__ void prep_kernel(const float* __restrict__ X, const int* __restrict__ slot_token,
                            uint4* __restrict__ Xg,
                            const float4* __restrict__ srcGu, uint2* __restrict__ dstGu,
                            const float4* __restrict__ srcD, uint2* __restrict__ dstD) {
  int bx = blockIdx.x;
  if (bx < GATHER_B) {
    int gid = bx * 256 + threadIdx.x;
    int row = gid >> 7, j = (gid & 127) << 3;
    int t = slot_token[row];
    uint4 o;
    if (t >= 0) {
      const float4* p = (const float4*)(X + (size_t)t * DIM + j);
      float4 a = p[0], b = p[1];
      o.x = pack2(a.x, a.y); o.y = pack2(a.z, a.w);
      o.z = pack2(b.x, b.y); o.w = pack2(b.z, b.w);
    } else {
      o = uint4{0u, 0u, 0u, 0u};
    }
    Xg[gid] = o;
  } else {
    const int n1 = NE * 2 * HID * DIM / 4;   // 8388608 float4s
    int i = (bx - GATHER_B) * 256 + threadIdx.x;
    float4 v; uint2* dp;
    if (i < n1) { v = srcGu[i]; dp = dstGu + i; }
    else        { v = srcD[i - n1]; dp = dstD + (i - n1); }
    uint2 o; o.x = pack2(v.x, v.y); o.y = pack2(v.z, v.w);
    *dp = o;
  }
}

// ---------- GEMM1: 128 rows x 128 cols (gate+up), BK=64, 32x32x16 MFMA ----------
// grid (16, 72)
__global__ __launch_bounds__(256, 2) void gemm1_kernel(
    const unsigned short* __restrict__ Xg,   // [MP, DIM]
    const unsigned short* __restrict__ Wgu,  // [NE, 2*HID, DIM]
    unsigned short* __restrict__ Hbuf,       // [MP, HID]
    const int* __restrict__ table) {
  int e = table[blockIdx.y];
  if (e < 0) return;
  const int tid = threadIdx.x;
  const int lane = tid & 63, wave = tid >> 6;
  const int wm = wave >> 1, wn = wave & 1;
  const int l31 = lane & 31, lh = lane >> 5;

  __shared__ bf16 As[128 * 64];
  __shared__ bf16 Bg[128 * 64];
  __shared__ bf16 Bu[128 * 64];

  const unsigned short* A_base  = Xg  + (size_t)blockIdx.y * 128 * DIM;
  const unsigned short* Wg_base = Wgu + (size_t)e * 2 * HID * DIM + (size_t)(blockIdx.x * 128) * DIM;
  const unsigned short* Wu_base = Wg_base + (size_t)HID * DIM;

  f32x16 accg[2][2] = {}; f32x16 accu[2][2] = {};

  for (int kt = 0; kt < DIM / 64; ++kt) {   // 16 iters
    const int kb = kt * 64;
#pragma unroll
    for (int i = 0; i < 12; ++i) {          // 3 tiles x 128 rows x 8 chunks
      int s = i * 256 + tid;
      int r = (s >> 3) & 127, pc = s & 7, gc = pc ^ (r & 7);
      const unsigned short* src; bf16* dst;
      if (i < 4)      { src = A_base;  dst = As; }
      else if (i < 8) { src = Wg_base; dst = Bg; }
      else            { src = Wu_base; dst = Bu; }
      cp16(src + (size_t)r * DIM + kb + gc * 8, (void*)(dst + r * 64 + pc * 8));
    }
    __syncthreads();
#pragma unroll
    for (int ks = 0; ks < 4; ++ks) {
      const int c = ks * 2 + lh;
      bf16x8 a[2], bg[2], bu[2];
#pragma unroll
      for (int t = 0; t < 2; ++t) {
        int ar = wm * 64 + t * 32 + l31;
        a[t]  = *(const bf16x8*)(As + ar * 64 + (c ^ (ar & 7)) * 8);
        int br = wn * 64 + t * 32 + l31;
        bg[t] = *(const bf16x8*)(Bg + br * 64 + (c ^ (br & 7)) * 8);
        bu[t] = *(const bf16x8*)(Bu + br * 64 + (c ^ (br & 7)) * 8);
      }
#pragma unroll
      for (int ti = 0; ti < 2; ++ti)
#pragma unroll
        for (int tj = 0; tj < 2; ++tj) {
          accg[ti][tj] = __builtin_amdgcn_mfma_f32_32x32x16_bf16(a[ti], bg[tj], accg[ti][tj], 0, 0, 0);
          accu[ti][tj] = __builtin_amdgcn_mfma_f32_32x32x16_bf16(a[ti], bu[tj], accu[ti][tj], 0, 0, 0);
        }
    }
    __syncthreads();
  }

  const int rowBase = blockIdx.y * 128 + wm * 64;
  const int colBase = blockIdx.x * 128 + wn * 64;
#pragma unroll
  for (int ti = 0; ti < 2; ++ti)
#pragma unroll
    for (int tj = 0; tj < 2; ++tj)
#pragma unroll
      for (int r = 0; r < 16; ++r) {
        int row = rowBase + ti * 32 + (r & 3) + 8 * (r >> 2) + 4 * lh;
        int col = colBase + tj * 32 + l31;
        float g = accg[ti][tj][r], u = accu[ti][tj][r];
        float s = g / (1.0f + __expf(-g));
        Hbuf[(size_t)row * HID + col] = f2bf(s * u);
      }
}

// ---------- GEMM2: O[kslice][slot] = H(kslice) * Wd^T, BK=64, 32x32x16 ----------
// grid (8, 72, 2)
__global__ __launch_bounds__(256, 2) void gemm2_kernel(
    const unsigned short* __restrict__ Hbuf, // [MP, HID]
    const unsigned short* __restrict__ Wd,   // [NE, OUTD, HID]
    unsigned short* __restrict__ O0,         // [MP, OUTD] bf16 partial (kslice 0)
    unsigned short* __restrict__ O1,         // kslice 1
    const int* __restrict__ table) {
  int e = table[blockIdx.y];
  if (e < 0) return;
  const int tid = threadIdx.x;
  const int lane = tid & 63, wave = tid >> 6;
  const int wm = wave >> 1, wn = wave & 1;
  const int l31 = lane & 31, lh = lane >> 5;
  const int kslice = blockIdx.z;

  __shared__ bf16 As[128 * 64];
  __shared__ bf16 Bs[128 * 64];

  const unsigned short* A_base = Hbuf + (size_t)blockIdx.y * 128 * HID + kslice * (HID / 2);
  const unsigned short* B_base = Wd + (size_t)e * OUTD * HID + (size_t)(blockIdx.x * 128) * HID
                               + kslice * (HID / 2);

  f32x16 acc[2][2] = {};

  for (int kt = 0; kt < (HID / 2) / 64; ++kt) {   // 16 iters
    const int kb = kt * 64;
#pragma unroll
    for (int i = 0; i < 8; ++i) {
      int s = i * 256 + tid;
      int r = (s >> 3) & 127, pc = s & 7, gc = pc ^ (r & 7);
      const unsigned short* src = (i < 4) ? A_base : B_base;
      bf16* dst = (i < 4) ? As : Bs;
      cp16(src + (size_t)r * HID + kb + gc * 8, (void*)(dst + r * 64 + pc * 8));
    }
    __syncthreads();
#pragma unroll
    for (int ks = 0; ks < 4; ++ks) {
      const int c = ks * 2 + lh;
      bf16x8 a[2], b[2];
#pragma unroll
      for (int t = 0; t < 2; ++t) {
        int ar = wm * 64 + t * 32 + l31;
        a[t] = *(const bf16x8*)(As + ar * 64 + (c ^ (ar & 7)) * 8);
        int br = wn * 64 + t * 32 + l31;
        b[t] = *(const bf16x8*)(Bs + br * 64 + (c ^ (br & 7)) * 8);
      }
#pragma unroll
      for (int ti = 0; ti < 2; ++ti)
#pragma unroll
        for (int tj = 0; tj < 2; ++tj)
          acc[ti][tj] = __builtin_amdgcn_mfma_f32_32x32x16_bf16(a[ti], b[tj], acc[ti][tj], 0, 0, 0);
    }
    __syncthreads();
  }

  unsigned short* O = kslice ? O1 : O0;
  const int rowBase = blockIdx.y * 128 + wm * 64;
  const int colBase = blockIdx.x * 128 + wn * 64;
#pragma unroll
  for (int ti = 0; ti < 2; ++ti)
#pragma unroll
    for (int tj = 0; tj < 2; ++tj)
#pragma unroll
      for (int r = 0; r < 16; ++r) {
        int row = rowBase + ti * 32 + (r & 3) + 8 * (r >> 2) + 4 * lh;
        int col = colBase + tj * 32 + l31;
        O[(size_t)row * OUTD + col] = f2bf(acc[ti][tj][r]);
      }
}

// ---------- combine: out[t] = w0*(O0[s0]+O1[s0]) + w1*(O0[s1]+O1[s1]) ----------
__global__ void combine_kernel(const unsigned short* __restrict__ O0,
                               const unsigned short* __restrict__ O1,
                               const int* __restrict__ tok2slot,
                               const float* __restrict__ wts, float4* __restrict__ out) {
  int t = blockIdx.x, c = threadIdx.x;   // 4096 x 256; 4 cols/thread
  int s0 = tok2slot[2 * t], s1 = tok2slot[2 * t + 1];
  float w0 = wts[2 * t], w1 = wts[2 * t + 1];
  uint2 a0 = ((const uint2*)(O0 + (size_t)s0 * OUTD))[c];
  uint2 b0 = ((const uint2*)(O1 + (size_t)s0 * OUTD))[c];
  uint2 a1 = ((const uint2*)(O0 + (size_t)s1 * OUTD))[c];
  uint2 b1 = ((const uint2*)(O1 + (size_t)s1 * OUTD))[c];
  float4 o;
  o.x = w0 * (bf2f(a0.x & 0xFFFF) + bf2f(b0.x & 0xFFFF)) + w1 * (bf2f(a1.x & 0xFFFF) + bf2f(b1.x & 0xFFFF));
  o.y = w0 * (bf2f(a0.x >> 16)    + bf2f(b0.x >> 16))    + w1 * (bf2f(a1.x >> 16)    + bf2f(b1.x >> 16));
  o.z = w0 * (bf2f(a0.y & 0xFFFF) + bf2f(b0.y & 0xFFFF)) + w1 * (bf2f(a1.y & 0xFFFF) + bf2f(b1.y & 0xFFFF));
  o.w = w0 * (bf2f(a0.y >> 16)    + bf2f(b0.y >> 16))    + w1 * (bf2f(a1.y >> 16)    + bf2f(b1.y >> 16));
  out[(size_t)t * (OUTD / 4) + c] = o;
}

extern "C" void kernel_launch(void* const* d_in, const int* in_sizes, int n_in,
                              void* d_out, int out_size, void* d_ws, size_t ws_size,
                              hipStream_t stream) {
  const float* X     = (const float*)d_in[0];
  const int*   idx   = (const int*)d_in[1];
  const float* wts   = (const float*)d_in[2];
  const float* WguF  = (const float*)d_in[3];
  const float* WdF   = (const float*)d_in[4];
  float* out = (float*)d_out;

  char* base = (char*)d_ws;
  unsigned short* Wgu = (unsigned short*)(base + WGU_OFF);
  unsigned short* Wd  = (unsigned short*)(base + WD_OFF);
  unsigned short* Xg  = (unsigned short*)(base + XG_OFF);
  unsigned short* Hb  = (unsigned short*)(base + H_OFF);
  unsigned short* O0  = (unsigned short*)(base + O0_OFF);   // alias Wgu (dead after gemm1)
  unsigned short* O1  = (unsigned short*)(base + O1_OFF);
  int* slot_token = (int*)(base + TK_OFF);
  int* table      = (int*)(base + META_OFF);
  int* tok2slot   = (int*)(base + T2S_OFF);

  route_kernel<<<1, 1024, 0, stream>>>(idx, table, slot_token, tok2slot);
  {
    const int convB = (NE * 2 * HID * DIM + NE * OUTD * HID) / 4 / 256;   // 49152
    prep_kernel<<<GATHER_B + convB, 256, 0, stream>>>(X, slot_token, (uint4*)Xg,
        (const float4*)WguF, (uint2*)Wgu, (const float4*)WdF, (uint2*)Wd);
  }
  gemm1_kernel<<<dim3(HID / 128, NBR), 256, 0, stream>>>(Xg, Wgu, Hb, table);
  gemm2_kernel<<<dim3(OUTD / 128, NBR, 2), 256, 0, stream>>>(Hb, Wd, O0, O1, table);
  combine_kernel<<<TOKS, 256, 0, stream>>>(O0, O1, tok2slot, wts, (float4*)out);
}

// Round 5
// 435.763 us; speedup vs baseline: 1.0200x; 1.0200x over previous
//
// R5: revert gemms to R3 16x16x32/BK=64 structure (98us gemm1); gemm2 K-split x2
// (1152 blocks, bf16 partial O-slices, combine sums); prep=gather+convert fused.
#include <hip/hip_runtime.h>
#include <stdint.h>

#define TOKS 4096
#define DIM  1024
#define HID  2048
#define OUTD 1024
#define NE   8
#define MP   9216
#define NBR  72

typedef __bf16 bf16;
typedef bf16 bf16x8 __attribute__((ext_vector_type(8)));
typedef float f32x4 __attribute__((ext_vector_type(4)));
typedef __attribute__((address_space(1))) void gvoid;
typedef __attribute__((address_space(3))) void lvoid;

// ---- workspace byte offsets ----
#define WGU_OFF  0ull                         // 64MB bf16 weights; O0/O1 bf16 (2x18.9MB) alias after gemm1
#define WD_OFF   (WGU_OFF + 67108864ull)
#define XG_OFF   (WD_OFF  + 33554432ull)      // MP*1024*2
#define H_OFF    (XG_OFF  + 18874368ull)      // MP*2048*2
#define TK_OFF   (H_OFF   + 37748736ull)      // MP*4
#define META_OFF (TK_OFF  + 36864ull)         // table NBR ints
#define T2S_OFF  (META_OFF + 1024ull)         // TOKS*2 ints
#define O0_OFF   WGU_OFF
#define O1_OFF   (WGU_OFF + 18874368ull)

__device__ __forceinline__ unsigned short f2bf(float f) {
  union { float f; unsigned u; } v; v.f = f;
  unsigned r = (v.u + 0x7FFFu + ((v.u >> 16) & 1u)) >> 16;
  return (unsigned short)r;
}
__device__ __forceinline__ float bf2f(unsigned short h) {
  union { unsigned u; float f; } v; v.u = ((unsigned)h) << 16; return v.f;
}
__device__ __forceinline__ unsigned pack2(float a, float b) {
  return (unsigned)f2bf(a) | ((unsigned)f2bf(b) << 16);
}
__device__ __forceinline__ void cp16(const void* g, void* l) {
  __builtin_amdgcn_global_load_lds((gvoid*)(void*)g, (lvoid*)l, 16, 0, 0);
}

// ---------- routing ----------
__global__ __launch_bounds__(1024) void route_kernel(const int* __restrict__ idx,
                                                     int* __restrict__ table,
                                                     int* __restrict__ slot_token,
                                                     int* __restrict__ tok2slot) {
  __shared__ int cnt[NE], offs[NE], cur[NE];
  const int tid = threadIdx.x, lane = tid & 63;
  for (int i = tid; i < MP; i += 1024) slot_token[i] = -1;
  if (tid < NE) cnt[tid] = 0;
  __syncthreads();
  int myE[8];
#pragma unroll
  for (int c = 0; c < 8; ++c) myE[c] = idx[c * 1024 + tid];
#pragma unroll
  for (int c = 0; c < 8; ++c) {
    int e = myE[c];
#pragma unroll
    for (int ex = 0; ex < NE; ++ex) {
      unsigned long long m = __ballot(e == ex);
      if (lane == 0 && m) atomicAdd(&cnt[ex], __popcll(m));
    }
  }
  __syncthreads();
  if (tid == 0) {
    int cum = 0;
    for (int e = 0; e < NE; ++e) {
      offs[e] = cum; cur[e] = 0;
      int nb = (cnt[e] + 127) >> 7;
      int bb = cum >> 7;
      for (int b = 0; b < nb; ++b) table[bb + b] = e;
      cum += nb << 7;
    }
    for (int b = cum >> 7; b < NBR; ++b) table[b] = -1;
  }
  __syncthreads();
#pragma unroll
  for (int c = 0; c < 8; ++c) {
    int e = myE[c];
    int pos = 0;
#pragma unroll
    for (int ex = 0; ex < NE; ++ex) {
      unsigned long long m = __ballot(e == ex);
      if (e == ex) {
        int rank = __popcll(m & ((1ull << lane) - 1ull));
        int leader = __ffsll(m) - 1;
        int base = 0;
        if (lane == leader) base = atomicAdd(&cur[ex], __popcll(m));
        base = __shfl(base, leader);
        pos = offs[ex] + base + rank;
      }
    }
    slot_token[pos] = (c * 1024 + tid) >> 1;
    tok2slot[c * 1024 + tid] = pos;
  }
}

// ---------- fused gather (X->Xg bf16) + weight convert ----------
#define GATHER_B 4608   // MP*128/256
__global__ void prep_kernel(const float* __restrict__ X, const int* __restrict__ slot_token,
                            uint4* __restrict__ Xg,
                            const float4* __restrict__ srcGu, uint2* __restrict__ dstGu,
                            const float4* __restrict__ srcD, uint2* __restrict__ dstD) {
  int bx = blockIdx.x;
  if (bx < GATHER_B) {
    int gid = bx * 256 + threadIdx.x;
    int row = gid >> 7, j = (gid & 127) << 3;
    int t = slot_token[row];
    uint4 o;
    if (t >= 0) {
      const float4* p = (const float4*)(X + (size_t)t * DIM + j);
      float4 a = p[0], b = p[1];
      o.x = pack2(a.x, a.y); o.y = pack2(a.z, a.w);
      o.z = pack2(b.x, b.y); o.w = pack2(b.z, b.w);
    } else {
      o = uint4{0u, 0u, 0u, 0u};
    }
    Xg[gid] = o;
  } else {
    const int n1 = NE * 2 * HID * DIM / 4;
    int i = (bx - GATHER_B) * 256 + threadIdx.x;
    float4 v; uint2* dp;
    if (i < n1) { v = srcGu[i]; dp = dstGu + i; }
    else        { v = srcD[i - n1]; dp = dstD + (i - n1); }
    uint2 o; o.x = pack2(v.x, v.y); o.y = pack2(v.z, v.w);
    *dp = o;
  }
}

__global__ void combine_kernel(const unsigned short* __restrict__ O0,
                               const unsigned short* __restrict__ O1,
                               const int* __restrict__ tok2slot,
                               const float* __restrict__ wts, float4* __restrict__ out) {
  int t = blockIdx.x, c = threadIdx.x;   // 4096 x 256; 4 cols/thread
  int s0 = tok2slot[2 * t], s1 = tok2slot[2 * t + 1];
  float w0 = wts[2 * t], w1 = wts[2 * t + 1];
  uint2 a0 = ((const uint2*)(O0 + (size_t)s0 * OUTD))[c];
  uint2 b0 = ((const uint2*)(O1 + (size_t)s0 * OUTD))[c];
  uint2 a1 = ((const uint2*)(O0 + (size_t)s1 * OUTD))[c];
  uint2 b1 = ((const uint2*)(O1 + (size_t)s1 * OUTD))[c];
  float4 o;
  o.x = w0 * (bf2f(a0.x & 0xFFFF) + bf2f(b0.x & 0xFFFF)) + w1 * (bf2f(a1.x & 0xFFFF) + bf2f(b1.x & 0xFFFF));
  o.y = w0 * (bf2f(a0.x >> 16)    + bf2f(b0.x >> 16))    + w1 * (bf2f(a1.x >> 16)    + bf2f(b1.x >> 16));
  o.z = w0 * (bf2f(a0.y & 0xFFFF) + bf2f(b0.y & 0xFFFF)) + w1 * (bf2f(a1.y & 0xFFFF) + bf2f(b1.y & 0xFFFF));
  o.w = w0 * (bf2f(a0.y >> 16)    + bf2f(b0.y >> 16))    + w1 * (bf2f(a1.y >> 16)    + bf2f(b1.y >> 16));
  out[(size_t)t * (OUTD / 4) + c] = o;
}

// ---------- GEMM1: h = silu(Xg*Wg^T) * (Xg*Wu^T), BK=64, 16x16x32 (R3) ----------
// grid (32, 72)
__global__ __launch_bounds__(256) void gemm1_kernel(
    const unsigned short* __restrict__ Xg,   // [MP, DIM]
    const unsigned short* __restrict__ Wgu,  // [NE, 2*HID, DIM]
    unsigned short* __restrict__ Hbuf,       // [MP, HID]
    const int* __restrict__ table) {
  int e = table[blockIdx.y];
  if (e < 0) return;
  const int tid = threadIdx.x;
  const int lane = tid & 63, wave = tid >> 6;
  const int wm = wave >> 1, wn = wave & 1;
  const int lr = lane & 15, quad = lane >> 4;

  __shared__ bf16 As[128 * 64];
  __shared__ bf16 Bg[64 * 64];
  __shared__ bf16 Bu[64 * 64];

  const unsigned short* A_base  = Xg  + (size_t)blockIdx.y * 128 * DIM;
  const unsigned short* Wg_base = Wgu + (size_t)e * 2 * HID * DIM + (size_t)(blockIdx.x * 64) * DIM;
  const unsigned short* Wu_base = Wg_base + (size_t)HID * DIM;

  f32x4 accg[4][2] = {}; f32x4 accu[4][2] = {};

  for (int kt = 0; kt < DIM / 64; ++kt) {   // 16 iters
    const int kb = kt * 64;
#pragma unroll
    for (int i = 0; i < 4; ++i) {
      int s = i * 256 + tid, row = s >> 3, pc = s & 7, gc = pc ^ (row & 7);
      cp16(A_base + (size_t)row * DIM + kb + gc * 8, (void*)(As + row * 64 + pc * 8));
    }
#pragma unroll
    for (int i = 0; i < 2; ++i) {
      int s = i * 256 + tid, row = s >> 3, pc = s & 7, gc = pc ^ (row & 7);
      cp16(Wg_base + (size_t)row * DIM + kb + gc * 8, (void*)(Bg + row * 64 + pc * 8));
      cp16(Wu_base + (size_t)row * DIM + kb + gc * 8, (void*)(Bu + row * 64 + pc * 8));
    }
    __syncthreads();
#pragma unroll
    for (int ks = 0; ks < 2; ++ks) {
      bf16x8 a[4], bg[2], bu[2];
#pragma unroll
      for (int i = 0; i < 4; ++i) {
        int row = wm * 64 + i * 16 + lr;
        int pc = (ks * 4 + quad) ^ (row & 7);
        a[i] = *(const bf16x8*)(As + row * 64 + pc * 8);
      }
#pragma unroll
      for (int j = 0; j < 2; ++j) {
        int row = wn * 32 + j * 16 + lr;
        int pc = (ks * 4 + quad) ^ (row & 7);
        bg[j] = *(const bf16x8*)(Bg + row * 64 + pc * 8);
        bu[j] = *(const bf16x8*)(Bu + row * 64 + pc * 8);
      }
#pragma unroll
      for (int i = 0; i < 4; ++i)
#pragma unroll
        for (int j = 0; j < 2; ++j) {
          accg[i][j] = __builtin_amdgcn_mfma_f32_16x16x32_bf16(a[i], bg[j], accg[i][j], 0, 0, 0);
          accu[i][j] = __builtin_amdgcn_mfma_f32_16x16x32_bf16(a[i], bu[j], accu[i][j], 0, 0, 0);
        }
    }
    __syncthreads();
  }

  const int rowBase = blockIdx.y * 128 + wm * 64;
  const int colBase = blockIdx.x * 64 + wn * 32;
#pragma unroll
  for (int i = 0; i < 4; ++i)
#pragma unroll
    for (int r = 0; r < 4; ++r) {
      int row = rowBase + i * 16 + quad * 4 + r;
#pragma unroll
      for (int j = 0; j < 2; ++j) {
        float g = accg[i][j][r], u = accu[i][j][r];
        float s = g / (1.0f + __expf(-g));
        Hbuf[(size_t)row * HID + colBase + j * 16 + lr] = f2bf(s * u);
      }
    }
}

// ---------- GEMM2: O[kslice][slot] = H(kslice)*Wd^T, BK=64, 16x16x32, K-split x2 ----------
// grid (8, 72, 2)
__global__ __launch_bounds__(256) void gemm2_kernel(
    const unsigned short* __restrict__ Hbuf, // [MP, HID]
    const unsigned short* __restrict__ Wd,   // [NE, OUTD, HID]
    unsigned short* __restrict__ O0,         // [MP, OUTD] bf16 partial
    unsigned short* __restrict__ O1,
    const int* __restrict__ table) {
  int e = table[blockIdx.y];
  if (e < 0) return;
  const int tid = threadIdx.x;
  const int lane = tid & 63, wave = tid >> 6;
  const int wm = wave >> 1, wn = wave & 1;
  const int lr = lane & 15, quad = lane >> 4;
  const int kslice = blockIdx.z;

  __shared__ bf16 As[128 * 64];
  __shared__ bf16 Bs[128 * 64];

  const unsigned short* A_base = Hbuf + (size_t)blockIdx.y * 128 * HID + kslice * (HID / 2);
  const unsigned short* B_base = Wd + (size_t)e * OUTD * HID + (size_t)(blockIdx.x * 128) * HID
                               + kslice * (HID / 2);

  f32x4 acc[4][4] = {};

  for (int kt = 0; kt < (HID / 2) / 64; ++kt) {   // 16 iters
    const int kb = kt * 64;
#pragma unroll
    for (int i = 0; i < 4; ++i) {
      int s = i * 256 + tid, row = s >> 3, pc = s & 7, gc = pc ^ (row & 7);
      cp16(A_base + (size_t)row * HID + kb + gc * 8, (void*)(As + row * 64 + pc * 8));
      cp16(B_base + (size_t)row * HID + kb + gc * 8, (void*)(Bs + row * 64 + pc * 8));
    }
    __syncthreads();
#pragma unroll
    for (int ks = 0; ks < 2; ++ks) {
      bf16x8 a[4], b[4];
#pragma unroll
      for (int i = 0; i < 4; ++i) {
        int row = wm * 64 + i * 16 + lr;
        int pc = (ks * 4 + quad) ^ (row & 7);
        a[i] = *(const bf16x8*)(As + row * 64 + pc * 8);
      }
#pragma unroll
      for (int j = 0; j < 4; ++j) {
        int row = wn * 64 + j * 16 + lr;
        int pc = (ks * 4 + quad) ^ (row & 7);
        b[j] = *(const bf16x8*)(Bs + row * 64 + pc * 8);
      }
#pragma unroll
      for (int i = 0; i < 4; ++i)
#pragma unroll
        for (int j = 0; j < 4; ++j)
          acc[i][j] = __builtin_amdgcn_mfma_f32_16x16x32_bf16(a[i], b[j], acc[i][j], 0, 0, 0);
    }
    __syncthreads();
  }

  unsigned short* O = kslice ? O1 : O0;
  const int rowBase = blockIdx.y * 128 + wm * 64;
  const int colBase = blockIdx.x * 128 + wn * 64;
#pragma unroll
  for (int i = 0; i < 4; ++i)
#pragma unroll
    for (int r = 0; r < 4; ++r) {
      int row = rowBase + i * 16 + quad * 4 + r;
      unsigned short* Orow = O + (size_t)row * OUTD + colBase;
#pragma unroll
      for (int j = 0; j < 4; ++j)
        Orow[j * 16 + lr] = f2bf(acc[i][j][r]);
    }
}

extern "C" void kernel_launch(void* const* d_in, const int* in_sizes, int n_in,
                              void* d_out, int out_size, void* d_ws, size_t ws_size,
                              hipStream_t stream) {
  const float* X     = (const float*)d_in[0];
  const int*   idx   = (const int*)d_in[1];
  const float* wts   = (const float*)d_in[2];
  const float* WguF  = (const float*)d_in[3];
  const float* WdF   = (const float*)d_in[4];
  float* out = (float*)d_out;

  char* base = (char*)d_ws;
  unsigned short* Wgu = (unsigned short*)(base + WGU_OFF);
  unsigned short* Wd  = (unsigned short*)(base + WD_OFF);
  unsigned short* Xg  = (unsigned short*)(base + XG_OFF);
  unsigned short* Hb  = (unsigned short*)(base + H_OFF);
  unsigned short* O0  = (unsigned short*)(base + O0_OFF);   // alias Wgu (dead after gemm1)
  unsigned short* O1  = (unsigned short*)(base + O1_OFF);
  int* slot_token = (int*)(base + TK_OFF);
  int* table      = (int*)(base + META_OFF);
  int* tok2slot   = (int*)(base + T2S_OFF);

  route_kernel<<<1, 1024, 0, stream>>>(idx, table, slot_token, tok2slot);
  {
    const int convB = (NE * 2 * HID * DIM + NE * OUTD * HID) / 4 / 256;
    prep_kernel<<<GATHER_B + convB, 256, 0, stream>>>(X, slot_token, (uint4*)Xg,
        (const float4*)WguF, (uint2*)Wgu, (const float4*)WdF, (uint2*)Wd);
  }
  gemm1_kernel<<<dim3(HID / 64, NBR), 256, 0, stream>>>(Xg, Wgu, Hb, table);
  gemm2_kernel<<<dim3(OUTD / 128, NBR, 2), 256, 0, stream>>>(Hb, Wd, O0, O1, table);
  combine_kernel<<<TOKS, 256, 0, stream>>>(O0, O1, tok2slot, wts, (float4*)out);
}